// Round 6
// baseline (571.182 us; speedup 1.0000x reference)
//
#include <hip/hip_runtime.h>
#include <hip/hip_bf16.h>
#include <hip/hip_fp16.h>

#define NODES 100000
#define INC 128
#define HIDC 128
#define EMBC 64
#define PREDH 256

typedef __attribute__((ext_vector_type(8))) _Float16 half8;
typedef __attribute__((ext_vector_type(2))) _Float16 half2v;
typedef __attribute__((ext_vector_type(4))) float f32x4;

// ---------------- degree (incoming, excl. self loop) ----------------
__global__ void k_deg(const int* __restrict__ ei, int* __restrict__ deg, int E) {
    int e = blockIdx.x * 256 + threadIdx.x;
    if (e >= E) return;
    atomicAdd(&deg[ei[E + e]], 1);
}

__global__ void k_dinv(const int* __restrict__ deg, float* __restrict__ dinv, int n) {
    int i = blockIdx.x * 256 + threadIdx.x;
    if (i >= n) return;
    float c = (float)(deg[i] + 1);   // +1 self loop
    dinv[i] = 1.0f / sqrtf(c);
}

// ---------------- exclusive scan (3 kernels) ----------------
__global__ __launch_bounds__(1024) void k_scan1(const int* __restrict__ deg,
                                                int* __restrict__ rowptr,
                                                int* __restrict__ bsum, int n) {
    __shared__ int tmp[1024];
    int tid = threadIdx.x;
    int i = blockIdx.x * 1024 + tid;
    int v = (i < n) ? deg[i] : 0;
    tmp[tid] = v;
    __syncthreads();
    for (int off = 1; off < 1024; off <<= 1) {
        int t = (tid >= off) ? tmp[tid - off] : 0;
        __syncthreads();
        tmp[tid] += t;
        __syncthreads();
    }
    if (i < n) rowptr[i] = tmp[tid] - v;          // exclusive
    if (tid == 1023) bsum[blockIdx.x] = tmp[1023];
}

__global__ __launch_bounds__(128) void k_scan2(int* __restrict__ bsum, int nb) {
    __shared__ int tmp[128];
    int tid = threadIdx.x;
    int v = (tid < nb) ? bsum[tid] : 0;
    tmp[tid] = v;
    __syncthreads();
    for (int off = 1; off < 128; off <<= 1) {
        int t = (tid >= off) ? tmp[tid - off] : 0;
        __syncthreads();
        tmp[tid] += t;
        __syncthreads();
    }
    if (tid < nb) bsum[tid] = tmp[tid] - v;       // exclusive block offsets
}

__global__ __launch_bounds__(1024) void k_scan3(int* __restrict__ rowptr,
                                                const int* __restrict__ bsum, int n) {
    int i = blockIdx.x * 1024 + threadIdx.x;
    if (i >= n) return;
    rowptr[i] += bsum[blockIdx.x];
}

// ---------------- bucketed CSR build ----------------
// bucket b = dst>>5 covers nodes [32b, 32b+32); its CSR segment is
// [rowptr[32b], rowptr[32b+32]) so cursors come straight from rowptr.
__global__ void k_bcur(const int* __restrict__ rowptr, int* __restrict__ bcur, int NB) {
    int b = blockIdx.x * 256 + threadIdx.x;
    if (b >= NB) return;
    bcur[b] = rowptr[b * 32];
}

// append packed (s<<5)|(d&31) into bucket d>>5 (consecutive addresses per bucket)
__global__ void k_binfill(const int* __restrict__ ei, int* __restrict__ bcur,
                          unsigned* __restrict__ buf, int E) {
    int e = blockIdx.x * 256 + threadIdx.x;
    if (e >= E) return;
    int s = ei[e], d = ei[E + e];
    int pos = atomicAdd(&bcur[d >> 5], 1);
    buf[pos] = ((unsigned)s << 5) | (unsigned)(d & 31);
}

// per-bucket local sort into CSR: 32 LDS cursors, contiguous ~2KB dst region
__global__ __launch_bounds__(256) void k_csr(const unsigned* __restrict__ buf,
                                             const int* __restrict__ rowptr,
                                             int* __restrict__ col, int n, int E) {
    __shared__ int curs[32];
    int b = blockIdx.x;
    int tid = threadIdx.x;
    int node0 = b * 32;
    if (tid < 32) {
        int nd = node0 + tid;
        curs[tid] = (nd < n) ? rowptr[nd] : E;
    }
    int start = rowptr[node0];
    int end = (node0 + 32 < n) ? rowptr[node0 + 32] : E;
    __syncthreads();
    for (int i = start + tid; i < end; i += 256) {
        unsigned v = buf[i];
        int pos = atomicAdd(&curs[v & 31u], 1);
        col[pos] = (int)(v >> 5);
    }
}

// ---------------- transpose + cvt: src f32 [K,N] -> dst f16 [N,K] ----------------
template <int K, int N>
__global__ void k_prept(const float* __restrict__ src, _Float16* __restrict__ dst) {
    int i = blockIdx.x * 256 + threadIdx.x;
    if (i >= K * N) return;
    int nn = i / K, kk = i % K;
    dst[i] = (_Float16)src[kk * N + nn];
}

// ---------------- MFMA matmul + dinv scale: O_f16[M,N] = (X[M,K] @ W[K,N]) * dinv[m] ----------------
template <int N, int K, bool XF32>
__global__ __launch_bounds__(256) void k_mmf(const void* __restrict__ Xv,
                                             const _Float16* __restrict__ WT,
                                             const float* __restrict__ dinv,
                                             _Float16* __restrict__ O, int M) {
    int tid = threadIdx.x;
    int wid = tid >> 6, lane = tid & 63;
    int lr = lane & 15, kg = lane >> 4;
    int row0 = blockIdx.x * 64 + wid * 16;
    int arow = min(row0 + lr, M - 1);
    const int NF = N / 16;
    f32x4 acc[NF];
#pragma unroll
    for (int nr = 0; nr < NF; nr++) acc[nr] = (f32x4){0.f, 0.f, 0.f, 0.f};

#pragma unroll
    for (int ks = 0; ks < K / 32; ks++) {
        half8 a;
        if (XF32) {
            const float* Xf = (const float*)Xv + (size_t)arow * K + ks * 32 + kg * 8;
            float4 x0 = *(const float4*)Xf;
            float4 x1 = *(const float4*)(Xf + 4);
            a[0] = (_Float16)x0.x; a[1] = (_Float16)x0.y;
            a[2] = (_Float16)x0.z; a[3] = (_Float16)x0.w;
            a[4] = (_Float16)x1.x; a[5] = (_Float16)x1.y;
            a[6] = (_Float16)x1.z; a[7] = (_Float16)x1.w;
        } else {
            a = *(const half8*)((const _Float16*)Xv + (size_t)arow * K + ks * 32 + kg * 8);
        }
#pragma unroll
        for (int nr = 0; nr < NF; nr++) {
            half8 b = *(const half8*)&WT[(size_t)(nr * 16 + lr) * K + ks * 32 + kg * 8];
            acc[nr] = __builtin_amdgcn_mfma_f32_16x16x32_f16(a, b, acc[nr], 0, 0, 0);
        }
    }

    int orow0 = row0 + kg * 4;
    float dv[4];
#pragma unroll
    for (int r = 0; r < 4; r++) dv[r] = dinv[min(orow0 + r, M - 1)];
#pragma unroll
    for (int nr = 0; nr < NF; nr++)
#pragma unroll
        for (int r = 0; r < 4; r++) {
            int orow = orow0 + r;
            if (orow < M)
                O[(size_t)orow * N + nr * 16 + lr] = (_Float16)(acc[nr][r] * dv[r]);
        }
}

// ---------------- gather aggregation over pre-scaled f16 rows ----------------
template <int C, bool RELU, typename OT>
__global__ __launch_bounds__(256) void k_gath(const _Float16* __restrict__ Hs,
                                              const float* __restrict__ dinv,
                                              const int* __restrict__ rowptr,
                                              const int* __restrict__ deg,
                                              const int* __restrict__ col,
                                              const float* __restrict__ b,
                                              OT* __restrict__ O, int n) {
    const int TPN = C / 2;                  // lanes per node, half2 each
    const int NPB = 256 / TPN;
    int node = blockIdx.x * NPB + threadIdx.x / TPN;
    int lane2 = threadIdx.x % TPN;
    if (node >= n) return;
    int start = rowptr[node];
    int cnt = deg[node];
    float dd = dinv[node];

    half2v hself = *(const half2v*)&Hs[(size_t)node * C + lane2 * 2];
    float ax = (float)hself[0], ay = (float)hself[1];

    for (int base = 0; base < cnt; base += TPN) {
        int m = min(cnt - base, TPN);
        int myc = (lane2 < m) ? col[start + base + lane2] : 0;
        int j = 0;
        for (; j + 1 < m; j += 2) {
            int s0 = __shfl(myc, j, TPN);
            int s1 = __shfl(myc, j + 1, TPN);
            half2v h0 = *(const half2v*)&Hs[(size_t)s0 * C + lane2 * 2];
            half2v h1 = *(const half2v*)&Hs[(size_t)s1 * C + lane2 * 2];
            ax += (float)h0[0] + (float)h1[0];
            ay += (float)h0[1] + (float)h1[1];
        }
        if (j < m) {
            int s0 = __shfl(myc, j, TPN);
            half2v h0 = *(const half2v*)&Hs[(size_t)s0 * C + lane2 * 2];
            ax += (float)h0[0];
            ay += (float)h0[1];
        }
    }

    float2 bb = ((const float2*)b)[lane2];
    float vx = ax * dd + bb.x;
    float vy = ay * dd + bb.y;
    if (RELU) { vx = fmaxf(vx, 0.f); vy = fmaxf(vy, 0.f); }
    if constexpr (sizeof(OT) == 2) {
        half2v o; o[0] = (_Float16)vx; o[1] = (_Float16)vy;
        *(half2v*)&((_Float16*)O)[(size_t)node * C + lane2 * 2] = o;
    } else {
        ((float2*)((float*)O + (size_t)node * C))[lane2] = make_float2(vx, vy);
    }
}

// ---------------- MFMA link-prediction head (unchanged, validated) ----------------
__global__ __launch_bounds__(256) void k_predm(const float* __restrict__ Z,      // [NODES,64] f32
                                               const int* __restrict__ eli,      // [2,P]
                                               const _Float16* __restrict__ WT,  // [256n][256k]
                                               const float* __restrict__ bm1,
                                               const float* __restrict__ Wm2,
                                               const float* __restrict__ bm2,
                                               float* __restrict__ out, int P) {
    __shared__ _Float16 pf[64][264];   // ~33.8 KB
    __shared__ float red[4][64];
    int tid = threadIdx.x;
    int p0 = blockIdx.x * 64;

    {
        int pr = tid >> 2, q = tid & 3;       // 4 threads/pair, 16 cols each
        int pg = p0 + pr;
        int s = 0, d = 0;
        if (pg < P) { s = eli[pg]; d = eli[P + pg]; }
        const float4* zs4 = (const float4*)(Z + (size_t)s * 64 + q * 16);
        const float4* zd4 = (const float4*)(Z + (size_t)d * 64 + q * 16);
#pragma unroll
        for (int j = 0; j < 4; ++j) {
            float4 a = zs4[j], b = zd4[j];
            int c = q * 16 + j * 4;
            pf[pr][c + 0] = (_Float16)a.x;
            pf[pr][c + 1] = (_Float16)a.y;
            pf[pr][c + 2] = (_Float16)a.z;
            pf[pr][c + 3] = (_Float16)a.w;
            pf[pr][64 + c + 0] = (_Float16)b.x;
            pf[pr][64 + c + 1] = (_Float16)b.y;
            pf[pr][64 + c + 2] = (_Float16)b.z;
            pf[pr][64 + c + 3] = (_Float16)b.w;
            pf[pr][128 + c + 0] = (_Float16)(a.x * b.x);
            pf[pr][128 + c + 1] = (_Float16)(a.y * b.y);
            pf[pr][128 + c + 2] = (_Float16)(a.z * b.z);
            pf[pr][128 + c + 3] = (_Float16)(a.w * b.w);
            pf[pr][192 + c + 0] = (_Float16)fabsf(a.x - b.x);
            pf[pr][192 + c + 1] = (_Float16)fabsf(a.y - b.y);
            pf[pr][192 + c + 2] = (_Float16)fabsf(a.z - b.z);
            pf[pr][192 + c + 3] = (_Float16)fabsf(a.w - b.w);
        }
    }
    __syncthreads();

    int wid = tid >> 6, lane = tid & 63;
    int lr = lane & 15, kg = lane >> 4;
    int n0 = wid * 64;

    float wmv[4], bmv[4];
#pragma unroll
    for (int nr = 0; nr < 4; nr++) {
        int nn = n0 + nr * 16 + lr;
        wmv[nr] = Wm2[nn];
        bmv[nr] = bm1[nn];
    }

    f32x4 acc[4][4];
#pragma unroll
    for (int mr = 0; mr < 4; mr++)
#pragma unroll
        for (int nr = 0; nr < 4; nr++) acc[mr][nr] = (f32x4){0.f, 0.f, 0.f, 0.f};

    for (int ks = 0; ks < 8; ks++) {
        half8 a[4], b[4];
#pragma unroll
        for (int mr = 0; mr < 4; mr++)
            a[mr] = *(const half8*)&pf[mr * 16 + lr][ks * 32 + kg * 8];
#pragma unroll
        for (int nr = 0; nr < 4; nr++)
            b[nr] = *(const half8*)&WT[(size_t)(n0 + nr * 16 + lr) * 256 + ks * 32 + kg * 8];
#pragma unroll
        for (int mr = 0; mr < 4; mr++)
#pragma unroll
            for (int nr = 0; nr < 4; nr++)
                acc[mr][nr] = __builtin_amdgcn_mfma_f32_16x16x32_f16(a[mr], b[nr], acc[mr][nr], 0, 0, 0);
    }

#pragma unroll
    for (int mr = 0; mr < 4; mr++) {
#pragma unroll
        for (int reg = 0; reg < 4; reg++) {
            float p = 0.f;
#pragma unroll
            for (int nr = 0; nr < 4; nr++)
                p += fmaxf(acc[mr][nr][reg] + bmv[nr], 0.f) * wmv[nr];
            p += __shfl_xor(p, 1);
            p += __shfl_xor(p, 2);
            p += __shfl_xor(p, 4);
            p += __shfl_xor(p, 8);
            if (lr == 0) red[wid][mr * 16 + kg * 4 + reg] = p;
        }
    }
    __syncthreads();
    if (tid < 64) {
        int pg = p0 + tid;
        if (pg < P)
            out[pg] = red[0][tid] + red[1][tid] + red[2][tid] + red[3][tid] + bm2[0];
    }
}

extern "C" void kernel_launch(void* const* d_in, const int* in_sizes, int n_in,
                              void* d_out, int out_size, void* d_ws, size_t ws_size,
                              hipStream_t stream) {
    const float* x   = (const float*)d_in[0];
    const int*   ei  = (const int*)d_in[1];
    const int*   eli = (const int*)d_in[2];
    const float* W1  = (const float*)d_in[3];
    const float* b1  = (const float*)d_in[4];
    const float* W2  = (const float*)d_in[5];
    const float* b2  = (const float*)d_in[6];
    const float* Wm1 = (const float*)d_in[7];
    const float* bm1 = (const float*)d_in[8];
    const float* Wm2 = (const float*)d_in[9];
    const float* bm2 = (const float*)d_in[10];
    float* out = (float*)d_out;

    const int n = NODES;
    const int E = in_sizes[1] / 2;
    const int P = in_sizes[2] / 2;
    const int NB = (n + 31) / 32;            // dst buckets of 32 nodes

    char* ws = (char*)d_ws;
    size_t off = 0;
    auto alloc = [&](size_t bytes) {
        size_t o = off;
        off += (bytes + 255) & ~(size_t)255;
        return o;
    };
    int*      deg    = (int*)(ws + alloc((size_t)n * 4));
    int*      rowptr = (int*)(ws + alloc((size_t)n * 4));
    int*      bcur   = (int*)(ws + alloc((size_t)NB * 4));
    unsigned* ebuf   = (unsigned*)(ws + alloc((size_t)E * 4));
    int*      colx   = (int*)(ws + alloc((size_t)E * 4));
    int*      bsum   = (int*)(ws + alloc(512 * 4));
    float*    dinv   = (float*)(ws + alloc((size_t)n * 4));
    _Float16* WmT    = (_Float16*)(ws + alloc((size_t)256 * 256 * 2));
    _Float16* W1T    = (_Float16*)(ws + alloc((size_t)128 * 128 * 2));
    _Float16* W2T    = (_Float16*)(ws + alloc((size_t)64 * 128 * 2));
    _Float16* Hs1    = (_Float16*)(ws + alloc((size_t)n * HIDC * 2));  // (x@W1)*dinv f16
    _Float16* C1     = (_Float16*)(ws + alloc((size_t)n * HIDC * 2));  // conv1 out f16
    _Float16* Hs2    = (_Float16*)(ws + alloc((size_t)n * EMBC * 2));  // (C1@W2)*dinv f16
    float*    Z      = (float*)(ws + alloc((size_t)n * EMBC * 4));     // conv2 out f32

    // ---- CSR build + weight prep ----
    hipMemsetAsync(deg, 0, (size_t)n * 4, stream);
    k_deg<<<(E + 255) / 256, 256, 0, stream>>>(ei, deg, E);
    k_prept<256, 256><<<(256 * 256 + 255) / 256, 256, 0, stream>>>(Wm1, WmT);
    k_prept<128, 128><<<(128 * 128 + 255) / 256, 256, 0, stream>>>(W1, W1T);
    k_prept<128, 64><<<(128 * 64 + 255) / 256, 256, 0, stream>>>(W2, W2T);
    int nb = (n + 1023) / 1024;
    k_scan1<<<nb, 1024, 0, stream>>>(deg, rowptr, bsum, n);
    k_scan2<<<1, 128, 0, stream>>>(bsum, nb);
    k_scan3<<<nb, 1024, 0, stream>>>(rowptr, bsum, n);
    k_bcur<<<(NB + 255) / 256, 256, 0, stream>>>(rowptr, bcur, NB);
    k_binfill<<<(E + 255) / 256, 256, 0, stream>>>(ei, bcur, ebuf, E);
    k_csr<<<NB, 256, 0, stream>>>(ebuf, rowptr, colx, n, E);
    k_dinv<<<(n + 255) / 256, 256, 0, stream>>>(deg, dinv, n);

    int mmGrid = (n + 63) / 64;

    // ---- conv1: Hs1 = (x@W1)*dinv ; C1 = relu(dinv*(Hs1[d]+sum Hs1[s]) + b1) ----
    k_mmf<HIDC, INC, true><<<mmGrid, 256, 0, stream>>>(x, W1T, dinv, Hs1, n);
    {
        const int NPB = 256 / (HIDC / 2);   // 4 nodes/block
        k_gath<HIDC, true, _Float16><<<(n + NPB - 1) / NPB, 256, 0, stream>>>(
            Hs1, dinv, rowptr, deg, colx, b1, C1, n);
    }

    // ---- conv2: Hs2 = (C1@W2)*dinv ; Z = dinv*(Hs2[d]+sum Hs2[s]) + b2 ----
    k_mmf<EMBC, HIDC, false><<<mmGrid, 256, 0, stream>>>(C1, W2T, dinv, Hs2, n);
    {
        const int NPB = 256 / (EMBC / 2);   // 8 nodes/block
        k_gath<EMBC, false, float><<<(n + NPB - 1) / NPB, 256, 0, stream>>>(
            Hs2, dinv, rowptr, deg, colx, b2, Z, n);
    }

    // ---- prediction head (MFMA f16) ----
    k_predm<<<(P + 63) / 64, 256, 0, stream>>>(Z, eli, WmT, bm1, Wm2, bm2, out, P);
}

// Round 8
// 469.372 us; speedup vs baseline: 1.2169x; 1.2169x over previous
//
#include <hip/hip_runtime.h>
#include <hip/hip_bf16.h>
#include <hip/hip_fp16.h>

#define NODES 100000
#define INC 128
#define HIDC 128
#define EMBC 64
#define PREDH 256

// coarse dst-buckets for the two-phase CSR build
#define BSH 9                 // 512 nodes per bucket
#define BNODES (1 << BSH)
#define MTILE 8192            // edges per multisplit block

typedef __attribute__((ext_vector_type(8))) _Float16 half8;
typedef __attribute__((ext_vector_type(2))) _Float16 half2v;
typedef __attribute__((ext_vector_type(4))) float f32x4;

// ---------------- degree (incoming, excl. self loop) ----------------
__global__ void k_deg(const int* __restrict__ ei, int* __restrict__ deg, int E) {
    int e = blockIdx.x * 256 + threadIdx.x;
    if (e >= E) return;
    atomicAdd(&deg[ei[E + e]], 1);
}

__global__ void k_dinv(const int* __restrict__ deg, float* __restrict__ dinv, int n) {
    int i = blockIdx.x * 256 + threadIdx.x;
    if (i >= n) return;
    float c = (float)(deg[i] + 1);   // +1 self loop
    dinv[i] = 1.0f / sqrtf(c);
}

// ---------------- exclusive scan (3 kernels) ----------------
__global__ __launch_bounds__(1024) void k_scan1(const int* __restrict__ deg,
                                                int* __restrict__ rowptr,
                                                int* __restrict__ bsum, int n) {
    __shared__ int tmp[1024];
    int tid = threadIdx.x;
    int i = blockIdx.x * 1024 + tid;
    int v = (i < n) ? deg[i] : 0;
    tmp[tid] = v;
    __syncthreads();
    for (int off = 1; off < 1024; off <<= 1) {
        int t = (tid >= off) ? tmp[tid - off] : 0;
        __syncthreads();
        tmp[tid] += t;
        __syncthreads();
    }
    if (i < n) rowptr[i] = tmp[tid] - v;          // exclusive
    if (tid == 1023) bsum[blockIdx.x] = tmp[1023];
}

__global__ __launch_bounds__(128) void k_scan2(int* __restrict__ bsum, int nb) {
    __shared__ int tmp[128];
    int tid = threadIdx.x;
    int v = (tid < nb) ? bsum[tid] : 0;
    tmp[tid] = v;
    __syncthreads();
    for (int off = 1; off < 128; off <<= 1) {
        int t = (tid >= off) ? tmp[tid - off] : 0;
        __syncthreads();
        tmp[tid] += t;
        __syncthreads();
    }
    if (tid < nb) bsum[tid] = tmp[tid] - v;       // exclusive block offsets
}

__global__ __launch_bounds__(1024) void k_scan3(int* __restrict__ rowptr,
                                                const int* __restrict__ bsum, int n) {
    int i = blockIdx.x * 1024 + threadIdx.x;
    if (i >= n) return;
    rowptr[i] += bsum[blockIdx.x];
}

// ---------------- bucket cursor init: gcur[b] = rowptr[b*BNODES] ----------------
__global__ void k_bcur(const int* __restrict__ rowptr, int* __restrict__ gcur, int NB) {
    int b = blockIdx.x * 256 + threadIdx.x;
    if (b >= NB) return;
    gcur[b] = rowptr[b << BSH];
}

// ---------------- block-aggregated multisplit into coarse buckets ----------------
// Each block: LDS histogram over NB buckets for its tile, ONE global atomic per
// (block,bucket) to reserve a contiguous run, then rank+write. Runs are written
// by a single CU into a contiguous region -> full 64B lines, no cross-XCD ping-pong.
template <int NB>
__global__ __launch_bounds__(256) void k_msplit(const int* __restrict__ ei,
                                                int* __restrict__ gcur,
                                                unsigned* __restrict__ ebuf, int E) {
    __shared__ int lcnt[NB];
    __shared__ int lbase[NB];
    int tid = threadIdx.x;
    int t0 = blockIdx.x * MTILE;
    int iend = min(t0 + MTILE, E);
    for (int i = tid; i < NB; i += 256) lcnt[i] = 0;
    __syncthreads();
    // phase A: count
    for (int i = t0 + tid; i < iend; i += 256)
        atomicAdd(&lcnt[ei[E + i] >> BSH], 1);
    __syncthreads();
    // reserve per-bucket runs (one global atomic per bucket)
    for (int i = tid; i < NB; i += 256) {
        int c = lcnt[i];
        lbase[i] = c ? atomicAdd(&gcur[i], c) : 0;
        lcnt[i] = 0;
    }
    __syncthreads();
    // phase B: rank & write packed (s << BSH) | (d & (BNODES-1))
    for (int i = t0 + tid; i < iend; i += 256) {
        int s = ei[i], d = ei[E + i];
        int b = d >> BSH;
        int r = atomicAdd(&lcnt[b], 1);
        ebuf[lbase[b] + r] = ((unsigned)s << BSH) | (unsigned)(d & (BNODES - 1));
    }
}

// ---------------- per-bucket CSR finalize: 512 LDS cursors, L2-local window ----------------
__global__ __launch_bounds__(256) void k_csrB(const unsigned* __restrict__ ebuf,
                                              const int* __restrict__ rowptr,
                                              int* __restrict__ col, int n, int E) {
    __shared__ int curs[BNODES];
    int b = blockIdx.x;
    int node0 = b << BSH;
    int tid = threadIdx.x;
    for (int i = tid; i < BNODES; i += 256) {
        int nd = node0 + i;
        curs[i] = (nd < n) ? rowptr[nd] : 0;
    }
    int start = rowptr[node0];
    int end = (node0 + BNODES < n) ? rowptr[node0 + BNODES] : E;
    __syncthreads();
    for (int i = start + tid; i < end; i += 256) {
        unsigned v = ebuf[i];
        int pos = atomicAdd(&curs[v & (unsigned)(BNODES - 1)], 1);
        col[pos] = (int)(v >> BSH);
    }
}

// ---------------- transpose + cvt: src f32 [K,N] -> dst f16 [N,K] ----------------
template <int K, int N>
__global__ void k_prept(const float* __restrict__ src, _Float16* __restrict__ dst) {
    int i = blockIdx.x * 256 + threadIdx.x;
    if (i >= K * N) return;
    int nn = i / K, kk = i % K;
    dst[i] = (_Float16)src[kk * N + nn];
}

// ---------------- MFMA matmul + dinv scale: O_f16[M,N] = (X[M,K] @ W[K,N]) * dinv[m] ----------------
template <int N, int K, bool XF32>
__global__ __launch_bounds__(256) void k_mmf(const void* __restrict__ Xv,
                                             const _Float16* __restrict__ WT,
                                             const float* __restrict__ dinv,
                                             _Float16* __restrict__ O, int M) {
    int tid = threadIdx.x;
    int wid = tid >> 6, lane = tid & 63;
    int lr = lane & 15, kg = lane >> 4;
    int row0 = blockIdx.x * 64 + wid * 16;
    int arow = min(row0 + lr, M - 1);
    const int NF = N / 16;
    f32x4 acc[NF];
#pragma unroll
    for (int nr = 0; nr < NF; nr++) acc[nr] = (f32x4){0.f, 0.f, 0.f, 0.f};

#pragma unroll
    for (int ks = 0; ks < K / 32; ks++) {
        half8 a;
        if (XF32) {
            const float* Xf = (const float*)Xv + (size_t)arow * K + ks * 32 + kg * 8;
            float4 x0 = *(const float4*)Xf;
            float4 x1 = *(const float4*)(Xf + 4);
            a[0] = (_Float16)x0.x; a[1] = (_Float16)x0.y;
            a[2] = (_Float16)x0.z; a[3] = (_Float16)x0.w;
            a[4] = (_Float16)x1.x; a[5] = (_Float16)x1.y;
            a[6] = (_Float16)x1.z; a[7] = (_Float16)x1.w;
        } else {
            a = *(const half8*)((const _Float16*)Xv + (size_t)arow * K + ks * 32 + kg * 8);
        }
#pragma unroll
        for (int nr = 0; nr < NF; nr++) {
            half8 b = *(const half8*)&WT[(size_t)(nr * 16 + lr) * K + ks * 32 + kg * 8];
            acc[nr] = __builtin_amdgcn_mfma_f32_16x16x32_f16(a, b, acc[nr], 0, 0, 0);
        }
    }

    int orow0 = row0 + kg * 4;
    float dv[4];
#pragma unroll
    for (int r = 0; r < 4; r++) dv[r] = dinv[min(orow0 + r, M - 1)];
#pragma unroll
    for (int nr = 0; nr < NF; nr++)
#pragma unroll
        for (int r = 0; r < 4; r++) {
            int orow = orow0 + r;
            if (orow < M)
                O[(size_t)orow * N + nr * 16 + lr] = (_Float16)(acc[nr][r] * dv[r]);
        }
}

// ---------------- gather aggregation over pre-scaled f16 rows ----------------
template <int C, bool RELU, typename OT>
__global__ __launch_bounds__(256) void k_gath(const _Float16* __restrict__ Hs,
                                              const float* __restrict__ dinv,
                                              const int* __restrict__ rowptr,
                                              const int* __restrict__ deg,
                                              const int* __restrict__ col,
                                              const float* __restrict__ b,
                                              OT* __restrict__ O, int n) {
    const int TPN = C / 2;                  // lanes per node, half2 each
    const int NPB = 256 / TPN;
    int node = blockIdx.x * NPB + threadIdx.x / TPN;
    int lane2 = threadIdx.x % TPN;
    if (node >= n) return;
    int start = rowptr[node];
    int cnt = deg[node];
    float dd = dinv[node];

    half2v hself = *(const half2v*)&Hs[(size_t)node * C + lane2 * 2];
    float ax = (float)hself[0], ay = (float)hself[1];

    for (int base = 0; base < cnt; base += TPN) {
        int m = min(cnt - base, TPN);
        int myc = (lane2 < m) ? col[start + base + lane2] : 0;
        int j = 0;
        for (; j + 1 < m; j += 2) {
            int s0 = __shfl(myc, j, TPN);
            int s1 = __shfl(myc, j + 1, TPN);
            half2v h0 = *(const half2v*)&Hs[(size_t)s0 * C + lane2 * 2];
            half2v h1 = *(const half2v*)&Hs[(size_t)s1 * C + lane2 * 2];
            ax += (float)h0[0] + (float)h1[0];
            ay += (float)h0[1] + (float)h1[1];
        }
        if (j < m) {
            int s0 = __shfl(myc, j, TPN);
            half2v h0 = *(const half2v*)&Hs[(size_t)s0 * C + lane2 * 2];
            ax += (float)h0[0];
            ay += (float)h0[1];
        }
    }

    float2 bb = ((const float2*)b)[lane2];
    float vx = ax * dd + bb.x;
    float vy = ay * dd + bb.y;
    if (RELU) { vx = fmaxf(vx, 0.f); vy = fmaxf(vy, 0.f); }
    if constexpr (sizeof(OT) == 2) {
        half2v o; o[0] = (_Float16)vx; o[1] = (_Float16)vy;
        *(half2v*)&((_Float16*)O)[(size_t)node * C + lane2 * 2] = o;
    } else {
        ((float2*)((float*)O + (size_t)node * C))[lane2] = make_float2(vx, vy);
    }
}

// ---------------- MFMA link-prediction head (unchanged, validated) ----------------
__global__ __launch_bounds__(256) void k_predm(const float* __restrict__ Z,      // [NODES,64] f32
                                               const int* __restrict__ eli,      // [2,P]
                                               const _Float16* __restrict__ WT,  // [256n][256k]
                                               const float* __restrict__ bm1,
                                               const float* __restrict__ Wm2,
                                               const float* __restrict__ bm2,
                                               float* __restrict__ out, int P) {
    __shared__ _Float16 pf[64][264];   // ~33.8 KB
    __shared__ float red[4][64];
    int tid = threadIdx.x;
    int p0 = blockIdx.x * 64;

    {
        int pr = tid >> 2, q = tid & 3;       // 4 threads/pair, 16 cols each
        int pg = p0 + pr;
        int s = 0, d = 0;
        if (pg < P) { s = eli[pg]; d = eli[P + pg]; }
        const float4* zs4 = (const float4*)(Z + (size_t)s * 64 + q * 16);
        const float4* zd4 = (const float4*)(Z + (size_t)d * 64 + q * 16);
#pragma unroll
        for (int j = 0; j < 4; ++j) {
            float4 a = zs4[j], b = zd4[j];
            int c = q * 16 + j * 4;
            pf[pr][c + 0] = (_Float16)a.x;
            pf[pr][c + 1] = (_Float16)a.y;
            pf[pr][c + 2] = (_Float16)a.z;
            pf[pr][c + 3] = (_Float16)a.w;
            pf[pr][64 + c + 0] = (_Float16)b.x;
            pf[pr][64 + c + 1] = (_Float16)b.y;
            pf[pr][64 + c + 2] = (_Float16)b.z;
            pf[pr][64 + c + 3] = (_Float16)b.w;
            pf[pr][128 + c + 0] = (_Float16)(a.x * b.x);
            pf[pr][128 + c + 1] = (_Float16)(a.y * b.y);
            pf[pr][128 + c + 2] = (_Float16)(a.z * b.z);
            pf[pr][128 + c + 3] = (_Float16)(a.w * b.w);
            pf[pr][192 + c + 0] = (_Float16)fabsf(a.x - b.x);
            pf[pr][192 + c + 1] = (_Float16)fabsf(a.y - b.y);
            pf[pr][192 + c + 2] = (_Float16)fabsf(a.z - b.z);
            pf[pr][192 + c + 3] = (_Float16)fabsf(a.w - b.w);
        }
    }
    __syncthreads();

    int wid = tid >> 6, lane = tid & 63;
    int lr = lane & 15, kg = lane >> 4;
    int n0 = wid * 64;

    float wmv[4], bmv[4];
#pragma unroll
    for (int nr = 0; nr < 4; nr++) {
        int nn = n0 + nr * 16 + lr;
        wmv[nr] = Wm2[nn];
        bmv[nr] = bm1[nn];
    }

    f32x4 acc[4][4];
#pragma unroll
    for (int mr = 0; mr < 4; mr++)
#pragma unroll
        for (int nr = 0; nr < 4; nr++) acc[mr][nr] = (f32x4){0.f, 0.f, 0.f, 0.f};

    for (int ks = 0; ks < 8; ks++) {
        half8 a[4], b[4];
#pragma unroll
        for (int mr = 0; mr < 4; mr++)
            a[mr] = *(const half8*)&pf[mr * 16 + lr][ks * 32 + kg * 8];
#pragma unroll
        for (int nr = 0; nr < 4; nr++)
            b[nr] = *(const half8*)&WT[(size_t)(n0 + nr * 16 + lr) * 256 + ks * 32 + kg * 8];
#pragma unroll
        for (int mr = 0; mr < 4; mr++)
#pragma unroll
            for (int nr = 0; nr < 4; nr++)
                acc[mr][nr] = __builtin_amdgcn_mfma_f32_16x16x32_f16(a[mr], b[nr], acc[mr][nr], 0, 0, 0);
    }

#pragma unroll
    for (int mr = 0; mr < 4; mr++) {
#pragma unroll
        for (int reg = 0; reg < 4; reg++) {
            float p = 0.f;
#pragma unroll
            for (int nr = 0; nr < 4; nr++)
                p += fmaxf(acc[mr][nr][reg] + bmv[nr], 0.f) * wmv[nr];
            p += __shfl_xor(p, 1);
            p += __shfl_xor(p, 2);
            p += __shfl_xor(p, 4);
            p += __shfl_xor(p, 8);
            if (lr == 0) red[wid][mr * 16 + kg * 4 + reg] = p;
        }
    }
    __syncthreads();
    if (tid < 64) {
        int pg = p0 + tid;
        if (pg < P)
            out[pg] = red[0][tid] + red[1][tid] + red[2][tid] + red[3][tid] + bm2[0];
    }
}

extern "C" void kernel_launch(void* const* d_in, const int* in_sizes, int n_in,
                              void* d_out, int out_size, void* d_ws, size_t ws_size,
                              hipStream_t stream) {
    const float* x   = (const float*)d_in[0];
    const int*   ei  = (const int*)d_in[1];
    const int*   eli = (const int*)d_in[2];
    const float* W1  = (const float*)d_in[3];
    const float* b1  = (const float*)d_in[4];
    const float* W2  = (const float*)d_in[5];
    const float* b2  = (const float*)d_in[6];
    const float* Wm1 = (const float*)d_in[7];
    const float* bm1 = (const float*)d_in[8];
    const float* Wm2 = (const float*)d_in[9];
    const float* bm2 = (const float*)d_in[10];
    float* out = (float*)d_out;

    const int n = NODES;
    const int E = in_sizes[1] / 2;
    const int P = in_sizes[2] / 2;
    const int NB = (n + BNODES - 1) / BNODES;   // 196 coarse buckets

    char* ws = (char*)d_ws;
    size_t off = 0;
    auto alloc = [&](size_t bytes) {
        size_t o = off;
        off += (bytes + 255) & ~(size_t)255;
        return o;
    };
    int*      deg    = (int*)(ws + alloc((size_t)n * 4));
    int*      rowptr = (int*)(ws + alloc((size_t)n * 4));
    int*      gcur   = (int*)(ws + alloc(512 * 4));
    unsigned* ebuf   = (unsigned*)(ws + alloc((size_t)E * 4));
    int*      colx   = (int*)(ws + alloc((size_t)E * 4));
    int*      bsum   = (int*)(ws + alloc(512 * 4));
    float*    dinv   = (float*)(ws + alloc((size_t)n * 4));
    _Float16* WmT    = (_Float16*)(ws + alloc((size_t)256 * 256 * 2));
    _Float16* W1T    = (_Float16*)(ws + alloc((size_t)128 * 128 * 2));
    _Float16* W2T    = (_Float16*)(ws + alloc((size_t)64 * 128 * 2));
    _Float16* Hs1    = (_Float16*)(ws + alloc((size_t)n * HIDC * 2));  // (x@W1)*dinv f16
    _Float16* C1     = (_Float16*)(ws + alloc((size_t)n * HIDC * 2));  // conv1 out f16
    _Float16* Hs2    = (_Float16*)(ws + alloc((size_t)n * EMBC * 2));  // (C1@W2)*dinv f16
    float*    Z      = (float*)(ws + alloc((size_t)n * EMBC * 4));     // conv2 out f32

    // ---- CSR build + weight prep ----
    hipMemsetAsync(deg, 0, (size_t)n * 4, stream);
    k_deg<<<(E + 255) / 256, 256, 0, stream>>>(ei, deg, E);
    k_prept<256, 256><<<(256 * 256 + 255) / 256, 256, 0, stream>>>(Wm1, WmT);
    k_prept<128, 128><<<(128 * 128 + 255) / 256, 256, 0, stream>>>(W1, W1T);
    k_prept<128, 64><<<(128 * 64 + 255) / 256, 256, 0, stream>>>(W2, W2T);
    int nb = (n + 1023) / 1024;
    k_scan1<<<nb, 1024, 0, stream>>>(deg, rowptr, bsum, n);
    k_scan2<<<1, 128, 0, stream>>>(bsum, nb);
    k_scan3<<<nb, 1024, 0, stream>>>(rowptr, bsum, n);
    k_bcur<<<(NB + 255) / 256, 256, 0, stream>>>(rowptr, gcur, NB);
    k_msplit<196><<<(E + MTILE - 1) / MTILE, 256, 0, stream>>>(ei, gcur, ebuf, E);
    k_csrB<<<NB, 256, 0, stream>>>(ebuf, rowptr, colx, n, E);
    k_dinv<<<(n + 255) / 256, 256, 0, stream>>>(deg, dinv, n);

    int mmGrid = (n + 63) / 64;

    // ---- conv1: Hs1 = (x@W1)*dinv ; C1 = relu(dinv*(Hs1[d]+sum Hs1[s]) + b1) ----
    k_mmf<HIDC, INC, true><<<mmGrid, 256, 0, stream>>>(x, W1T, dinv, Hs1, n);
    {
        const int NPB = 256 / (HIDC / 2);   // 4 nodes/block
        k_gath<HIDC, true, _Float16><<<(n + NPB - 1) / NPB, 256, 0, stream>>>(
            Hs1, dinv, rowptr, deg, colx, b1, C1, n);
    }

    // ---- conv2: Hs2 = (C1@W2)*dinv ; Z = dinv*(Hs2[d]+sum Hs2[s]) + b2 ----
    k_mmf<EMBC, HIDC, false><<<mmGrid, 256, 0, stream>>>(C1, W2T, dinv, Hs2, n);
    {
        const int NPB = 256 / (EMBC / 2);   // 8 nodes/block
        k_gath<EMBC, false, float><<<(n + NPB - 1) / NPB, 256, 0, stream>>>(
            Hs2, dinv, rowptr, deg, colx, b2, Z, n);
    }

    // ---- prediction head (MFMA f16) ----
    k_predm<<<(P + 63) / 64, 256, 0, stream>>>(Z, eli, WmT, bm1, Wm2, bm2, out, P);
}

// Round 9
// 459.326 us; speedup vs baseline: 1.2435x; 1.0219x over previous
//
#include <hip/hip_runtime.h>
#include <hip/hip_bf16.h>
#include <hip/hip_fp16.h>

#define NODES 100000
#define INC 128
#define HIDC 128
#define EMBC 64
#define PREDH 256

// coarse dst-buckets for the two-phase CSR build
#define BSH 9                 // 512 nodes per bucket
#define BNODES (1 << BSH)
#define MTILE 8192            // edges per multisplit block

typedef __attribute__((ext_vector_type(8))) _Float16 half8;
typedef __attribute__((ext_vector_type(4))) float f32x4;

// ---------------- degree (incoming, excl. self loop) ----------------
__global__ void k_deg(const int* __restrict__ ei, int* __restrict__ deg, int E) {
    int e = blockIdx.x * 256 + threadIdx.x;
    if (e >= E) return;
    atomicAdd(&deg[ei[E + e]], 1);
}

// ---------------- exclusive scan ----------------
__global__ __launch_bounds__(1024) void k_scan1(const int* __restrict__ deg,
                                                int* __restrict__ rowptr,
                                                int* __restrict__ bsum, int n) {
    __shared__ int tmp[1024];
    int tid = threadIdx.x;
    int i = blockIdx.x * 1024 + tid;
    int v = (i < n) ? deg[i] : 0;
    tmp[tid] = v;
    __syncthreads();
    for (int off = 1; off < 1024; off <<= 1) {
        int t = (tid >= off) ? tmp[tid - off] : 0;
        __syncthreads();
        tmp[tid] += t;
        __syncthreads();
    }
    if (i < n) rowptr[i] = tmp[tid] - v;          // exclusive
    if (tid == 1023) bsum[blockIdx.x] = tmp[1023];
}

__global__ __launch_bounds__(128) void k_scan2(int* __restrict__ bsum, int nb) {
    __shared__ int tmp[128];
    int tid = threadIdx.x;
    int v = (tid < nb) ? bsum[tid] : 0;
    tmp[tid] = v;
    __syncthreads();
    for (int off = 1; off < 128; off <<= 1) {
        int t = (tid >= off) ? tmp[tid - off] : 0;
        __syncthreads();
        tmp[tid] += t;
        __syncthreads();
    }
    if (tid < nb) bsum[tid] = tmp[tid] - v;       // exclusive block offsets
}

// scan3 fused with dinv + bucket-cursor init
__global__ __launch_bounds__(1024) void k_scan3(int* __restrict__ rowptr,
                                                const int* __restrict__ bsum,
                                                const int* __restrict__ deg,
                                                float* __restrict__ dinv,
                                                int* __restrict__ gcur, int n) {
    int i = blockIdx.x * 1024 + threadIdx.x;
    if (i >= n) return;
    int r = rowptr[i] + bsum[blockIdx.x];
    rowptr[i] = r;
    dinv[i] = rsqrtf((float)(deg[i] + 1));        // +1 self loop
    if ((i & (BNODES - 1)) == 0) gcur[i >> BSH] = r;
}

// ---------------- block-aggregated multisplit into coarse buckets ----------------
template <int NB>
__global__ __launch_bounds__(256) void k_msplit(const int* __restrict__ ei,
                                                int* __restrict__ gcur,
                                                unsigned* __restrict__ ebuf, int E) {
    __shared__ int lcnt[NB];
    __shared__ int lbase[NB];
    int tid = threadIdx.x;
    int t0 = blockIdx.x * MTILE;
    int iend = min(t0 + MTILE, E);
    for (int i = tid; i < NB; i += 256) lcnt[i] = 0;
    __syncthreads();
    for (int i = t0 + tid; i < iend; i += 256)
        atomicAdd(&lcnt[ei[E + i] >> BSH], 1);
    __syncthreads();
    for (int i = tid; i < NB; i += 256) {
        int c = lcnt[i];
        lbase[i] = c ? atomicAdd(&gcur[i], c) : 0;
        lcnt[i] = 0;
    }
    __syncthreads();
    for (int i = t0 + tid; i < iend; i += 256) {
        int s = ei[i], d = ei[E + i];
        int b = d >> BSH;
        int r = atomicAdd(&lcnt[b], 1);
        ebuf[lbase[b] + r] = ((unsigned)s << BSH) | (unsigned)(d & (BNODES - 1));
    }
}

// ---------------- per-bucket CSR finalize ----------------
__global__ __launch_bounds__(256) void k_csrB(const unsigned* __restrict__ ebuf,
                                              const int* __restrict__ rowptr,
                                              int* __restrict__ col, int n, int E) {
    __shared__ int curs[BNODES];
    int b = blockIdx.x;
    int node0 = b << BSH;
    int tid = threadIdx.x;
    for (int i = tid; i < BNODES; i += 256) {
        int nd = node0 + i;
        curs[i] = (nd < n) ? rowptr[nd] : 0;
    }
    int start = rowptr[node0];
    int end = (node0 + BNODES < n) ? rowptr[node0 + BNODES] : E;
    __syncthreads();
    for (int i = start + tid; i < end; i += 256) {
        unsigned v = ebuf[i];
        int pos = atomicAdd(&curs[v & (unsigned)(BNODES - 1)], 1);
        col[pos] = (int)(v >> BSH);
    }
}

// ---------------- fused weight transpose+cvt (Wm1, W1, W2 in one launch) ----------------
__global__ void k_prepall(const float* __restrict__ Wm1, const float* __restrict__ W1,
                          const float* __restrict__ W2, _Float16* __restrict__ WmT,
                          _Float16* __restrict__ W1T, _Float16* __restrict__ W2T) {
    int i = blockIdx.x * 256 + threadIdx.x;
    if (i < 256 * 256) {
        int nn = i >> 8, kk = i & 255;
        WmT[i] = (_Float16)Wm1[kk * 256 + nn];
    } else if (i < 256 * 256 + 128 * 128) {
        int j = i - 256 * 256;
        int nn = j >> 7, kk = j & 127;
        W1T[j] = (_Float16)W1[kk * 128 + nn];
    } else if (i < 256 * 256 + 128 * 128 + 64 * 128) {
        int j = i - 256 * 256 - 128 * 128;
        int nn = j >> 7, kk = j & 127;
        W2T[j] = (_Float16)W2[kk * 64 + nn];
    }
}

// ---------------- MFMA matmul + dinv scale: O_f16[M,N] = (X[M,K] @ W[K,N]) * dinv[m] ----------------
template <int N, int K, bool XF32>
__global__ __launch_bounds__(256) void k_mmf(const void* __restrict__ Xv,
                                             const _Float16* __restrict__ WT,
                                             const float* __restrict__ dinv,
                                             _Float16* __restrict__ O, int M) {
    int tid = threadIdx.x;
    int wid = tid >> 6, lane = tid & 63;
    int lr = lane & 15, kg = lane >> 4;
    int row0 = blockIdx.x * 64 + wid * 16;
    int arow = min(row0 + lr, M - 1);
    const int NF = N / 16;
    f32x4 acc[NF];
#pragma unroll
    for (int nr = 0; nr < NF; nr++) acc[nr] = (f32x4){0.f, 0.f, 0.f, 0.f};

#pragma unroll
    for (int ks = 0; ks < K / 32; ks++) {
        half8 a;
        if (XF32) {
            const float* Xf = (const float*)Xv + (size_t)arow * K + ks * 32 + kg * 8;
            float4 x0 = *(const float4*)Xf;
            float4 x1 = *(const float4*)(Xf + 4);
            a[0] = (_Float16)x0.x; a[1] = (_Float16)x0.y;
            a[2] = (_Float16)x0.z; a[3] = (_Float16)x0.w;
            a[4] = (_Float16)x1.x; a[5] = (_Float16)x1.y;
            a[6] = (_Float16)x1.z; a[7] = (_Float16)x1.w;
        } else {
            a = *(const half8*)((const _Float16*)Xv + (size_t)arow * K + ks * 32 + kg * 8);
        }
#pragma unroll
        for (int nr = 0; nr < NF; nr++) {
            half8 b = *(const half8*)&WT[(size_t)(nr * 16 + lr) * K + ks * 32 + kg * 8];
            acc[nr] = __builtin_amdgcn_mfma_f32_16x16x32_f16(a, b, acc[nr], 0, 0, 0);
        }
    }

    int orow0 = row0 + kg * 4;
    float dv[4];
#pragma unroll
    for (int r = 0; r < 4; r++) dv[r] = dinv[min(orow0 + r, M - 1)];
#pragma unroll
    for (int nr = 0; nr < NF; nr++)
#pragma unroll
        for (int r = 0; r < 4; r++) {
            int orow = orow0 + r;
            if (orow < M)
                O[(size_t)orow * N + nr * 16 + lr] = (_Float16)(acc[nr][r] * dv[r]);
        }
}

// ---------------- wide-load gather: wave = 1 node, C/8-lane groups, half8 rows ----------------
// O[d] = act( dinv[d] * ( Hs[d] + sum_{s in N(d)} Hs[s] ) + b ),  all rows f16.
template <int C, bool RELU>
__global__ __launch_bounds__(256) void k_gath(const _Float16* __restrict__ Hs,
                                              const float* __restrict__ dinv,
                                              const int* __restrict__ rowptr,
                                              const int* __restrict__ deg,
                                              const int* __restrict__ col,
                                              const float* __restrict__ b,
                                              _Float16* __restrict__ O, int n) {
    const int LPR = C / 8;            // lanes per row (16 for C=128, 8 for C=64)
    const int EPI = 64 / LPR;         // edges per wave-iteration (4 or 8)
    int wid = threadIdx.x >> 6;
    int node = blockIdx.x * 4 + wid;
    if (node >= n) return;
    int lane = threadIdx.x & 63;
    int grp = lane / LPR;             // edge slot within iteration
    int lane2 = lane % LPR;           // 16B chunk within row
    int start = rowptr[node];
    int cnt = deg[node];
    float dd = dinv[node];

    float acc[8] = {0.f, 0.f, 0.f, 0.f, 0.f, 0.f, 0.f, 0.f};
    for (int j = 0; j < cnt; j += EPI) {
        int e = j + grp;
        if (e < cnt) {
            int s = col[start + e];
            half8 h = *(const half8*)&Hs[(size_t)s * C + lane2 * 8];
#pragma unroll
            for (int t = 0; t < 8; t++) acc[t] += (float)h[t];
        }
    }
    // cross-group reduce (groups hold partial sums of the same col range)
#pragma unroll
    for (int t = 0; t < 8; t++) {
        float v = acc[t];
#pragma unroll
        for (int off = LPR; off < 64; off <<= 1)
            v += __shfl_xor(v, off);
        acc[t] = v;
    }
    if (grp == 0) {
        half8 hs = *(const half8*)&Hs[(size_t)node * C + lane2 * 8];
        const float* bp = b + lane2 * 8;
        half8 o;
#pragma unroll
        for (int t = 0; t < 8; t++) {
            float v = (acc[t] + (float)hs[t]) * dd + bp[t];
            if (RELU) v = fmaxf(v, 0.f);
            o[t] = (_Float16)v;
        }
        *(half8*)&O[(size_t)node * C + lane2 * 8] = o;
    }
}

// ---------------- MFMA link-prediction head (Z now f16) ----------------
__global__ __launch_bounds__(256) void k_predm(const _Float16* __restrict__ Z,   // [NODES,64] f16
                                               const int* __restrict__ eli,      // [2,P]
                                               const _Float16* __restrict__ WT,  // [256n][256k]
                                               const float* __restrict__ bm1,
                                               const float* __restrict__ Wm2,
                                               const float* __restrict__ bm2,
                                               float* __restrict__ out, int P) {
    __shared__ _Float16 pf[64][264];   // ~33.8 KB
    __shared__ float red[4][64];
    int tid = threadIdx.x;
    int p0 = blockIdx.x * 64;

    {
        int pr = tid >> 2, q = tid & 3;       // 4 threads/pair, 16 cols each
        int pg = p0 + pr;
        int s = 0, d = 0;
        if (pg < P) { s = eli[pg]; d = eli[P + pg]; }
        const half8* zs8 = (const half8*)(Z + (size_t)s * 64 + q * 16);
        const half8* zd8 = (const half8*)(Z + (size_t)d * 64 + q * 16);
#pragma unroll
        for (int h = 0; h < 2; ++h) {
            half8 za = zs8[h], zb = zd8[h];
            int c = q * 16 + h * 8;
#pragma unroll
            for (int t = 0; t < 8; ++t) {
                float a = (float)za[t], bb = (float)zb[t];
                pf[pr][c + t] = za[t];
                pf[pr][64 + c + t] = zb[t];
                pf[pr][128 + c + t] = (_Float16)(a * bb);
                pf[pr][192 + c + t] = (_Float16)fabsf(a - bb);
            }
        }
    }
    __syncthreads();

    int wid = tid >> 6, lane = tid & 63;
    int lr = lane & 15, kg = lane >> 4;
    int n0 = wid * 64;

    float wmv[4], bmv[4];
#pragma unroll
    for (int nr = 0; nr < 4; nr++) {
        int nn = n0 + nr * 16 + lr;
        wmv[nr] = Wm2[nn];
        bmv[nr] = bm1[nn];
    }

    f32x4 acc[4][4];
#pragma unroll
    for (int mr = 0; mr < 4; mr++)
#pragma unroll
        for (int nr = 0; nr < 4; nr++) acc[mr][nr] = (f32x4){0.f, 0.f, 0.f, 0.f};

    for (int ks = 0; ks < 8; ks++) {
        half8 a[4], b[4];
#pragma unroll
        for (int mr = 0; mr < 4; mr++)
            a[mr] = *(const half8*)&pf[mr * 16 + lr][ks * 32 + kg * 8];
#pragma unroll
        for (int nr = 0; nr < 4; nr++)
            b[nr] = *(const half8*)&WT[(size_t)(n0 + nr * 16 + lr) * 256 + ks * 32 + kg * 8];
#pragma unroll
        for (int mr = 0; mr < 4; mr++)
#pragma unroll
            for (int nr = 0; nr < 4; nr++)
                acc[mr][nr] = __builtin_amdgcn_mfma_f32_16x16x32_f16(a[mr], b[nr], acc[mr][nr], 0, 0, 0);
    }

#pragma unroll
    for (int mr = 0; mr < 4; mr++) {
#pragma unroll
        for (int reg = 0; reg < 4; reg++) {
            float p = 0.f;
#pragma unroll
            for (int nr = 0; nr < 4; nr++)
                p += fmaxf(acc[mr][nr][reg] + bmv[nr], 0.f) * wmv[nr];
            p += __shfl_xor(p, 1);
            p += __shfl_xor(p, 2);
            p += __shfl_xor(p, 4);
            p += __shfl_xor(p, 8);
            if (lr == 0) red[wid][mr * 16 + kg * 4 + reg] = p;
        }
    }
    __syncthreads();
    if (tid < 64) {
        int pg = p0 + tid;
        if (pg < P)
            out[pg] = red[0][tid] + red[1][tid] + red[2][tid] + red[3][tid] + bm2[0];
    }
}

extern "C" void kernel_launch(void* const* d_in, const int* in_sizes, int n_in,
                              void* d_out, int out_size, void* d_ws, size_t ws_size,
                              hipStream_t stream) {
    const float* x   = (const float*)d_in[0];
    const int*   ei  = (const int*)d_in[1];
    const int*   eli = (const int*)d_in[2];
    const float* W1  = (const float*)d_in[3];
    const float* b1  = (const float*)d_in[4];
    const float* W2  = (const float*)d_in[5];
    const float* b2  = (const float*)d_in[6];
    const float* Wm1 = (const float*)d_in[7];
    const float* bm1 = (const float*)d_in[8];
    const float* Wm2 = (const float*)d_in[9];
    const float* bm2 = (const float*)d_in[10];
    float* out = (float*)d_out;

    const int n = NODES;
    const int E = in_sizes[1] / 2;
    const int P = in_sizes[2] / 2;
    const int NB = (n + BNODES - 1) / BNODES;   // 196 coarse buckets

    char* ws = (char*)d_ws;
    size_t off = 0;
    auto alloc = [&](size_t bytes) {
        size_t o = off;
        off += (bytes + 255) & ~(size_t)255;
        return o;
    };
    int*      deg    = (int*)(ws + alloc((size_t)n * 4));
    int*      rowptr = (int*)(ws + alloc((size_t)n * 4));
    int*      gcur   = (int*)(ws + alloc(512 * 4));
    unsigned* ebuf   = (unsigned*)(ws + alloc((size_t)E * 4));
    int*      colx   = (int*)(ws + alloc((size_t)E * 4));
    int*      bsum   = (int*)(ws + alloc(512 * 4));
    float*    dinv   = (float*)(ws + alloc((size_t)n * 4));
    _Float16* WmT    = (_Float16*)(ws + alloc((size_t)256 * 256 * 2));
    _Float16* W1T    = (_Float16*)(ws + alloc((size_t)128 * 128 * 2));
    _Float16* W2T    = (_Float16*)(ws + alloc((size_t)64 * 128 * 2));
    _Float16* Hs1    = (_Float16*)(ws + alloc((size_t)n * HIDC * 2));  // (x@W1)*dinv f16
    _Float16* C1     = (_Float16*)(ws + alloc((size_t)n * HIDC * 2));  // conv1 out f16
    _Float16* Hs2    = (_Float16*)(ws + alloc((size_t)n * EMBC * 2));  // (C1@W2)*dinv f16
    _Float16* Z      = (_Float16*)(ws + alloc((size_t)n * EMBC * 2));  // conv2 out f16

    // ---- CSR build + weight prep ----
    hipMemsetAsync(deg, 0, (size_t)n * 4, stream);
    k_deg<<<(E + 255) / 256, 256, 0, stream>>>(ei, deg, E);
    {
        int tot = 256 * 256 + 128 * 128 + 64 * 128;
        k_prepall<<<(tot + 255) / 256, 256, 0, stream>>>(Wm1, W1, W2, WmT, W1T, W2T);
    }
    int nb = (n + 1023) / 1024;
    k_scan1<<<nb, 1024, 0, stream>>>(deg, rowptr, bsum, n);
    k_scan2<<<1, 128, 0, stream>>>(bsum, nb);
    k_scan3<<<nb, 1024, 0, stream>>>(rowptr, bsum, deg, dinv, gcur, n);
    k_msplit<196><<<(E + MTILE - 1) / MTILE, 256, 0, stream>>>(ei, gcur, ebuf, E);
    k_csrB<<<NB, 256, 0, stream>>>(ebuf, rowptr, colx, n, E);

    int mmGrid = (n + 63) / 64;

    // ---- conv1 ----
    k_mmf<HIDC, INC, true><<<mmGrid, 256, 0, stream>>>(x, W1T, dinv, Hs1, n);
    k_gath<HIDC, true><<<(n + 3) / 4, 256, 0, stream>>>(Hs1, dinv, rowptr, deg, colx, b1, C1, n);

    // ---- conv2 ----
    k_mmf<EMBC, HIDC, false><<<mmGrid, 256, 0, stream>>>(C1, W2T, dinv, Hs2, n);
    k_gath<EMBC, false><<<(n + 3) / 4, 256, 0, stream>>>(Hs2, dinv, rowptr, deg, colx, b2, Z, n);

    // ---- prediction head (MFMA f16) ----
    k_predm<<<(P + 63) / 64, 256, 0, stream>>>(Z, eli, WmT, bm1, Wm2, bm2, out, P);
}

// Round 10
// 382.750 us; speedup vs baseline: 1.4923x; 1.2001x over previous
//
#include <hip/hip_runtime.h>
#include <hip/hip_bf16.h>
#include <hip/hip_fp16.h>

#define NODES 100000
#define INC 128
#define HIDC 128
#define EMBC 64
#define PREDH 256

// coarse dst-buckets for the two-phase CSR build
#define BSH 9                 // 512 nodes per bucket
#define BNODES (1 << BSH)
#define MTILE 8192            // edges per multisplit block

typedef __attribute__((ext_vector_type(8))) _Float16 half8;
typedef __attribute__((ext_vector_type(4))) float f32x4;

// ---------------- bucket histogram (LDS-aggregated, 196 global atomics/block) ----------------
template <int NB>
__global__ __launch_bounds__(256) void k_bcnt(const int* __restrict__ ei,
                                              int* __restrict__ gcnt, int E) {
    __shared__ int lcnt[NB];
    int tid = threadIdx.x;
    int t0 = blockIdx.x * MTILE;
    int iend = min(t0 + MTILE, E);
    for (int i = tid; i < NB; i += 256) lcnt[i] = 0;
    __syncthreads();
    for (int i = t0 + tid; i < iend; i += 256)
        atomicAdd(&lcnt[ei[E + i] >> BSH], 1);
    __syncthreads();
    for (int i = tid; i < NB; i += 256)
        if (lcnt[i]) atomicAdd(&gcnt[i], lcnt[i]);
}

// ---------------- 196-wide exclusive scan -> gbase[NB+1], gcur ----------------
template <int NB>
__global__ __launch_bounds__(256) void k_bscan(const int* __restrict__ gcnt,
                                               int* __restrict__ gbase,
                                               int* __restrict__ gcur, int E) {
    __shared__ int tmp[256];
    int tid = threadIdx.x;
    int v = (tid < NB) ? gcnt[tid] : 0;
    tmp[tid] = v;
    __syncthreads();
    for (int off = 1; off < 256; off <<= 1) {
        int t = (tid >= off) ? tmp[tid - off] : 0;
        __syncthreads();
        tmp[tid] += t;
        __syncthreads();
    }
    if (tid < NB) {
        int e = tmp[tid] - v;
        gbase[tid] = e;
        gcur[tid] = e;
    }
    if (tid == NB) gbase[NB] = E;
}

// ---------------- block-aggregated multisplit into coarse buckets ----------------
template <int NB>
__global__ __launch_bounds__(256) void k_msplit(const int* __restrict__ ei,
                                                int* __restrict__ gcur,
                                                unsigned* __restrict__ ebuf, int E) {
    __shared__ int lcnt[NB];
    __shared__ int lbase[NB];
    int tid = threadIdx.x;
    int t0 = blockIdx.x * MTILE;
    int iend = min(t0 + MTILE, E);
    for (int i = tid; i < NB; i += 256) lcnt[i] = 0;
    __syncthreads();
    for (int i = t0 + tid; i < iend; i += 256)
        atomicAdd(&lcnt[ei[E + i] >> BSH], 1);
    __syncthreads();
    for (int i = tid; i < NB; i += 256) {
        int c = lcnt[i];
        lbase[i] = c ? atomicAdd(&gcur[i], c) : 0;
        lcnt[i] = 0;
    }
    __syncthreads();
    for (int i = t0 + tid; i < iend; i += 256) {
        int s = ei[i], d = ei[E + i];
        int b = d >> BSH;
        int r = atomicAdd(&lcnt[b], 1);
        ebuf[lbase[b] + r] = ((unsigned)s << BSH) | (unsigned)(d & (BNODES - 1));
    }
}

// ---------------- per-bucket: degree + rowptr + dinv + CSR placement ----------------
__global__ __launch_bounds__(256) void k_csrB2(const unsigned* __restrict__ ebuf,
                                               const int* __restrict__ gbase,
                                               int* __restrict__ rowptr,
                                               int* __restrict__ deg,
                                               float* __restrict__ dinv,
                                               int* __restrict__ col, int n) {
    __shared__ int cnt[BNODES];
    __shared__ int psum[256];
    __shared__ int curs[BNODES];
    int b = blockIdx.x;
    int tid = threadIdx.x;
    int node0 = b << BSH;
    int base = gbase[b];
    int end = gbase[b + 1];
    cnt[2 * tid] = 0;
    cnt[2 * tid + 1] = 0;
    __syncthreads();
    // pass 1: local degree histogram
    for (int i = base + tid; i < end; i += 256)
        atomicAdd(&cnt[ebuf[i] & (unsigned)(BNODES - 1)], 1);
    __syncthreads();
    // 512-wide exclusive scan via 256 pair-sums
    int a0 = cnt[2 * tid], a1 = cnt[2 * tid + 1];
    int pair = a0 + a1;
    psum[tid] = pair;
    __syncthreads();
    for (int off = 1; off < 256; off <<= 1) {
        int t = (tid >= off) ? psum[tid - off] : 0;
        __syncthreads();
        psum[tid] += t;
        __syncthreads();
    }
    int excl = psum[tid] - pair;
    // write rowptr/deg/dinv, init cursors (global positions)
    {
        int g0 = base + excl;
        int g1 = g0 + a0;
        int nd0 = node0 + 2 * tid, nd1 = nd0 + 1;
        if (nd0 < n) { rowptr[nd0] = g0; deg[nd0] = a0; dinv[nd0] = rsqrtf((float)(a0 + 1)); }
        if (nd1 < n) { rowptr[nd1] = g1; deg[nd1] = a1; dinv[nd1] = rsqrtf((float)(a1 + 1)); }
        curs[2 * tid] = g0;
        curs[2 * tid + 1] = g1;
    }
    __syncthreads();
    // pass 2: place columns
    for (int i = base + tid; i < end; i += 256) {
        unsigned v = ebuf[i];
        int pos = atomicAdd(&curs[v & (unsigned)(BNODES - 1)], 1);
        col[pos] = (int)(v >> BSH);
    }
}

// ---------------- fused weight transpose+cvt (Wm1, W1, W2 in one launch) ----------------
__global__ void k_prepall(const float* __restrict__ Wm1, const float* __restrict__ W1,
                          const float* __restrict__ W2, _Float16* __restrict__ WmT,
                          _Float16* __restrict__ W1T, _Float16* __restrict__ W2T) {
    int i = blockIdx.x * 256 + threadIdx.x;
    if (i < 256 * 256) {
        int nn = i >> 8, kk = i & 255;
        WmT[i] = (_Float16)Wm1[kk * 256 + nn];
    } else if (i < 256 * 256 + 128 * 128) {
        int j = i - 256 * 256;
        int nn = j >> 7, kk = j & 127;
        W1T[j] = (_Float16)W1[kk * 128 + nn];
    } else if (i < 256 * 256 + 128 * 128 + 64 * 128) {
        int j = i - 256 * 256 - 128 * 128;
        int nn = j >> 7, kk = j & 127;
        W2T[j] = (_Float16)W2[kk * 64 + nn];
    }
}

// ---------------- MFMA matmul + dinv scale: O_f16[M,N] = (X[M,K] @ W[K,N]) * dinv[m] ----------------
template <int N, int K, bool XF32>
__global__ __launch_bounds__(256) void k_mmf(const void* __restrict__ Xv,
                                             const _Float16* __restrict__ WT,
                                             const float* __restrict__ dinv,
                                             _Float16* __restrict__ O, int M) {
    int tid = threadIdx.x;
    int wid = tid >> 6, lane = tid & 63;
    int lr = lane & 15, kg = lane >> 4;
    int row0 = blockIdx.x * 64 + wid * 16;
    int arow = min(row0 + lr, M - 1);
    const int NF = N / 16;
    f32x4 acc[NF];
#pragma unroll
    for (int nr = 0; nr < NF; nr++) acc[nr] = (f32x4){0.f, 0.f, 0.f, 0.f};

#pragma unroll
    for (int ks = 0; ks < K / 32; ks++) {
        half8 a;
        if (XF32) {
            const float* Xf = (const float*)Xv + (size_t)arow * K + ks * 32 + kg * 8;
            float4 x0 = *(const float4*)Xf;
            float4 x1 = *(const float4*)(Xf + 4);
            a[0] = (_Float16)x0.x; a[1] = (_Float16)x0.y;
            a[2] = (_Float16)x0.z; a[3] = (_Float16)x0.w;
            a[4] = (_Float16)x1.x; a[5] = (_Float16)x1.y;
            a[6] = (_Float16)x1.z; a[7] = (_Float16)x1.w;
        } else {
            a = *(const half8*)((const _Float16*)Xv + (size_t)arow * K + ks * 32 + kg * 8);
        }
#pragma unroll
        for (int nr = 0; nr < NF; nr++) {
            half8 b = *(const half8*)&WT[(size_t)(nr * 16 + lr) * K + ks * 32 + kg * 8];
            acc[nr] = __builtin_amdgcn_mfma_f32_16x16x32_f16(a, b, acc[nr], 0, 0, 0);
        }
    }

    int orow0 = row0 + kg * 4;
    float dv[4];
#pragma unroll
    for (int r = 0; r < 4; r++) dv[r] = dinv[min(orow0 + r, M - 1)];
#pragma unroll
    for (int nr = 0; nr < NF; nr++)
#pragma unroll
        for (int r = 0; r < 4; r++) {
            int orow = orow0 + r;
            if (orow < M)
                O[(size_t)orow * N + nr * 16 + lr] = (_Float16)(acc[nr][r] * dv[r]);
        }
}

// ---------------- wide-load gather, 2x-unrolled for MLP depth ----------------
// O[d] = act( dinv[d] * ( Hs[d] + sum_{s in N(d)} Hs[s] ) + b ),  all rows f16.
template <int C, bool RELU>
__global__ __launch_bounds__(256) void k_gath(const _Float16* __restrict__ Hs,
                                              const float* __restrict__ dinv,
                                              const int* __restrict__ rowptr,
                                              const int* __restrict__ deg,
                                              const int* __restrict__ col,
                                              const float* __restrict__ b,
                                              _Float16* __restrict__ O, int n) {
    const int LPR = C / 8;            // lanes per row (16 for C=128, 8 for C=64)
    const int EPI = 64 / LPR;         // edges per wave-iteration (4 or 8)
    int wid = threadIdx.x >> 6;
    int node = blockIdx.x * 4 + wid;
    if (node >= n) return;
    int lane = threadIdx.x & 63;
    int grp = lane / LPR;             // edge slot within iteration
    int lane2 = lane % LPR;           // 16B chunk within row
    int start = rowptr[node];
    int cnt = deg[node];
    float dd = dinv[node];

    float acc[8] = {0.f, 0.f, 0.f, 0.f, 0.f, 0.f, 0.f, 0.f};
    int j = 0;
    // main loop: 2 independent row loads in flight per lane (2KB/wave)
    for (; j + 2 * EPI <= cnt; j += 2 * EPI) {
        int s0 = col[start + j + grp];
        int s1 = col[start + j + EPI + grp];
        half8 h0 = *(const half8*)&Hs[(size_t)s0 * C + lane2 * 8];
        half8 h1 = *(const half8*)&Hs[(size_t)s1 * C + lane2 * 8];
#pragma unroll
        for (int t = 0; t < 8; t++) acc[t] += (float)h0[t] + (float)h1[t];
    }
    for (; j < cnt; j += EPI) {
        int e = j + grp;
        if (e < cnt) {
            int s = col[start + e];
            half8 h = *(const half8*)&Hs[(size_t)s * C + lane2 * 8];
#pragma unroll
            for (int t = 0; t < 8; t++) acc[t] += (float)h[t];
        }
    }
    // cross-group reduce (groups hold partial sums of the same col range)
#pragma unroll
    for (int t = 0; t < 8; t++) {
        float v = acc[t];
#pragma unroll
        for (int off = LPR; off < 64; off <<= 1)
            v += __shfl_xor(v, off);
        acc[t] = v;
    }
    if (grp == 0) {
        half8 hs = *(const half8*)&Hs[(size_t)node * C + lane2 * 8];
        const float* bp = b + lane2 * 8;
        half8 o;
#pragma unroll
        for (int t = 0; t < 8; t++) {
            float v = (acc[t] + (float)hs[t]) * dd + bp[t];
            if (RELU) v = fmaxf(v, 0.f);
            o[t] = (_Float16)v;
        }
        *(half8*)&O[(size_t)node * C + lane2 * 8] = o;
    }
}

// ---------------- MFMA link-prediction head (Z f16) ----------------
__global__ __launch_bounds__(256) void k_predm(const _Float16* __restrict__ Z,   // [NODES,64] f16
                                               const int* __restrict__ eli,      // [2,P]
                                               const _Float16* __restrict__ WT,  // [256n][256k]
                                               const float* __restrict__ bm1,
                                               const float* __restrict__ Wm2,
                                               const float* __restrict__ bm2,
                                               float* __restrict__ out, int P) {
    __shared__ _Float16 pf[64][264];   // ~33.8 KB
    __shared__ float red[4][64];
    int tid = threadIdx.x;
    int p0 = blockIdx.x * 64;

    {
        int pr = tid >> 2, q = tid & 3;       // 4 threads/pair, 16 cols each
        int pg = p0 + pr;
        int s = 0, d = 0;
        if (pg < P) { s = eli[pg]; d = eli[P + pg]; }
        const half8* zs8 = (const half8*)(Z + (size_t)s * 64 + q * 16);
        const half8* zd8 = (const half8*)(Z + (size_t)d * 64 + q * 16);
#pragma unroll
        for (int h = 0; h < 2; ++h) {
            half8 za = zs8[h], zb = zd8[h];
            int c = q * 16 + h * 8;
#pragma unroll
            for (int t = 0; t < 8; ++t) {
                float a = (float)za[t], bb = (float)zb[t];
                pf[pr][c + t] = za[t];
                pf[pr][64 + c + t] = zb[t];
                pf[pr][128 + c + t] = (_Float16)(a * bb);
                pf[pr][192 + c + t] = (_Float16)fabsf(a - bb);
            }
        }
    }
    __syncthreads();

    int wid = tid >> 6, lane = tid & 63;
    int lr = lane & 15, kg = lane >> 4;
    int n0 = wid * 64;

    float wmv[4], bmv[4];
#pragma unroll
    for (int nr = 0; nr < 4; nr++) {
        int nn = n0 + nr * 16 + lr;
        wmv[nr] = Wm2[nn];
        bmv[nr] = bm1[nn];
    }

    f32x4 acc[4][4];
#pragma unroll
    for (int mr = 0; mr < 4; mr++)
#pragma unroll
        for (int nr = 0; nr < 4; nr++) acc[mr][nr] = (f32x4){0.f, 0.f, 0.f, 0.f};

    for (int ks = 0; ks < 8; ks++) {
        half8 a[4], b[4];
#pragma unroll
        for (int mr = 0; mr < 4; mr++)
            a[mr] = *(const half8*)&pf[mr * 16 + lr][ks * 32 + kg * 8];
#pragma unroll
        for (int nr = 0; nr < 4; nr++)
            b[nr] = *(const half8*)&WT[(size_t)(n0 + nr * 16 + lr) * 256 + ks * 32 + kg * 8];
#pragma unroll
        for (int mr = 0; mr < 4; mr++)
#pragma unroll
            for (int nr = 0; nr < 4; nr++)
                acc[mr][nr] = __builtin_amdgcn_mfma_f32_16x16x32_f16(a[mr], b[nr], acc[mr][nr], 0, 0, 0);
    }

#pragma unroll
    for (int mr = 0; mr < 4; mr++) {
#pragma unroll
        for (int reg = 0; reg < 4; reg++) {
            float p = 0.f;
#pragma unroll
            for (int nr = 0; nr < 4; nr++)
                p += fmaxf(acc[mr][nr][reg] + bmv[nr], 0.f) * wmv[nr];
            p += __shfl_xor(p, 1);
            p += __shfl_xor(p, 2);
            p += __shfl_xor(p, 4);
            p += __shfl_xor(p, 8);
            if (lr == 0) red[wid][mr * 16 + kg * 4 + reg] = p;
        }
    }
    __syncthreads();
    if (tid < 64) {
        int pg = p0 + tid;
        if (pg < P)
            out[pg] = red[0][tid] + red[1][tid] + red[2][tid] + red[3][tid] + bm2[0];
    }
}

extern "C" void kernel_launch(void* const* d_in, const int* in_sizes, int n_in,
                              void* d_out, int out_size, void* d_ws, size_t ws_size,
                              hipStream_t stream) {
    const float* x   = (const float*)d_in[0];
    const int*   ei  = (const int*)d_in[1];
    const int*   eli = (const int*)d_in[2];
    const float* W1  = (const float*)d_in[3];
    const float* b1  = (const float*)d_in[4];
    const float* W2  = (const float*)d_in[5];
    const float* b2  = (const float*)d_in[6];
    const float* Wm1 = (const float*)d_in[7];
    const float* bm1 = (const float*)d_in[8];
    const float* Wm2 = (const float*)d_in[9];
    const float* bm2 = (const float*)d_in[10];
    float* out = (float*)d_out;

    const int n = NODES;
    const int E = in_sizes[1] / 2;
    const int P = in_sizes[2] / 2;
    const int NB = (n + BNODES - 1) / BNODES;   // 196 coarse buckets

    char* ws = (char*)d_ws;
    size_t off = 0;
    auto alloc = [&](size_t bytes) {
        size_t o = off;
        off += (bytes + 255) & ~(size_t)255;
        return o;
    };
    int*      deg    = (int*)(ws + alloc((size_t)n * 4));
    int*      rowptr = (int*)(ws + alloc((size_t)n * 4));
    int*      gcnt   = (int*)(ws + alloc(512 * 4));
    int*      gbase  = (int*)(ws + alloc(512 * 4));
    int*      gcur   = (int*)(ws + alloc(512 * 4));
    unsigned* ebuf   = (unsigned*)(ws + alloc((size_t)E * 4));
    int*      colx   = (int*)(ws + alloc((size_t)E * 4));
    float*    dinv   = (float*)(ws + alloc((size_t)n * 4));
    _Float16* WmT    = (_Float16*)(ws + alloc((size_t)256 * 256 * 2));
    _Float16* W1T    = (_Float16*)(ws + alloc((size_t)128 * 128 * 2));
    _Float16* W2T    = (_Float16*)(ws + alloc((size_t)64 * 128 * 2));
    _Float16* Hs1    = (_Float16*)(ws + alloc((size_t)n * HIDC * 2));  // (x@W1)*dinv f16
    _Float16* C1     = (_Float16*)(ws + alloc((size_t)n * HIDC * 2));  // conv1 out f16
    _Float16* Hs2    = (_Float16*)(ws + alloc((size_t)n * EMBC * 2));  // (C1@W2)*dinv f16
    _Float16* Z      = (_Float16*)(ws + alloc((size_t)n * EMBC * 2));  // conv2 out f16

    // ---- CSR build + weight prep ----
    hipMemsetAsync(gcnt, 0, 512 * 4, stream);
    {
        int tot = 256 * 256 + 128 * 128 + 64 * 128;
        k_prepall<<<(tot + 255) / 256, 256, 0, stream>>>(Wm1, W1, W2, WmT, W1T, W2T);
    }
    int mgrid = (E + MTILE - 1) / MTILE;
    k_bcnt<196><<<mgrid, 256, 0, stream>>>(ei, gcnt, E);
    k_bscan<196><<<1, 256, 0, stream>>>(gcnt, gbase, gcur, E);
    k_msplit<196><<<mgrid, 256, 0, stream>>>(ei, gcur, ebuf, E);
    k_csrB2<<<NB, 256, 0, stream>>>(ebuf, gbase, rowptr, deg, dinv, colx, n);

    int mmGrid = (n + 63) / 64;

    // ---- conv1 ----
    k_mmf<HIDC, INC, true><<<mmGrid, 256, 0, stream>>>(x, W1T, dinv, Hs1, n);
    k_gath<HIDC, true><<<(n + 3) / 4, 256, 0, stream>>>(Hs1, dinv, rowptr, deg, colx, b1, C1, n);

    // ---- conv2 ----
    k_mmf<EMBC, HIDC, false><<<mmGrid, 256, 0, stream>>>(C1, W2T, dinv, Hs2, n);
    k_gath<EMBC, false><<<(n + 3) / 4, 256, 0, stream>>>(Hs2, dinv, rowptr, deg, colx, b2, Z, n);

    // ---- prediction head (MFMA f16) ----
    k_predm<<<(P + 63) / 64, 256, 0, stream>>>(Z, eli, WmT, bm1, Wm2, bm2, out, P);
}